// Round 5
// baseline (313.438 us; speedup 1.0000x reference)
//
#include <hip/hip_runtime.h>

// Problem dims (fixed by the reference): B=256, T=100, D=1024, H=128, C=5
constexpr int Bsz = 256;
constexpr int Tn  = 100;
constexpr int Dn  = 1024;
constexpr int Hn  = 128;
constexpr int Cn  = 5;

// float64 values of np.exp(-1/10), np.exp(-1/20)
#define D1 0.9048374180359595731642491
#define D2 0.9512294245007140090914253

typedef double double4_t __attribute__((ext_vector_type(4)));

// ---------------------------------------------------------------------------
// W1 f32 -> f64 into workspace (1024*128 = 131072 elements)
// ---------------------------------------------------------------------------
__global__ __launch_bounds__(256) void cvt_w1(const float* __restrict__ W1,
                                              double* __restrict__ W1d)
{
  const int i = (blockIdx.x * 256 + threadIdx.x) * 4;
  float4 v = *(const float4*)(W1 + i);
  double2 a, b;
  a.x = (double)v.x; a.y = (double)v.y;
  b.x = (double)v.z; b.y = (double)v.w;
  *(double2*)(W1d + i)     = a;
  *(double2*)(W1d + i + 2) = b;
}

// ---------------------------------------------------------------------------
// Phase 1 (MFMA f64): Hc[r,128] += X[rows, kq*256:+256] @ W1d[slice]
//
// R13: counters said MfmaUtil=52% = 41.6TF / ~78.6TF f64-matrix peak, with
// VALUBusy=8%, HBM=12% -> pure latency exposure. Per k0-iter: 4 MFMA (64cy
// of pipe) vs B-loads from L2 (~200cy) prefetched only 1 iter (64cy) ahead
// and same-iter LDS a-reads (~120cy). 4 waves/SIMD can't hide that by TLP.
// Fix: explicit rolling-register software pipeline, fully unrolled so all
// indices are compile-time (no scratch):
//   * B (L2):  depth-4 prefetch  (256cy lookahead >= 200cy L2 latency)
//   * A (LDS): depth-2 prefetch  (128cy lookahead >= 120cy LDS latency)
// VGPR 56 -> ~80, still < 128 so 16 waves/CU occupancy is preserved.
// SQ_LDS_BANK_CONFLICT=1.64M is exactly 2 counts/ds_read_b32 = the benign
// 64-lane/32-bank 2-pass accounting (free per m136) — not a real stall.
// Unchanged: [m][k] KPAD=132 LDS, b128 staging writes, 4 blocks/CU,
// TILE_M=32, KSPL=4 atomic epilogue, D-layout probe.
// ---------------------------------------------------------------------------
constexpr int TILE_M = 32;
constexpr int KSPL   = 4;
constexpr int KH     = Dn / KSPL;     // 256 k per block
constexpr int SC     = 128;           // staging sub-chunk (k)
constexpr int NS     = KH / SC;       // 2
constexpr int KPAD   = 132;           // 128 k + 4 pad (f32)

__global__ __launch_bounds__(256) void gemm_mfma_f64(
    const float* __restrict__ X, const double* __restrict__ W1d,
    double* __restrict__ Hc, int t0, int Tc)
{
  // As[buf][m][k] : 2 * 32 * 132 * 4 = 33792 B
  __shared__ __align__(16) float As[2][TILE_M][KPAD];

  const int tid   = threadIdx.x;
  const int mt    = blockIdx.x >> 2;
  const int kspl  = blockIdx.x & 3;
  const int m0    = mt * TILE_M;
  const int kbase = kspl * KH;

  // staging: thread t -> A row rA=t>>3 (0..31), float4 k-group c8=t&7 (+ j*8)
  const int rA = tid >> 3;
  const int c8 = tid & 7;
  const int rc   = m0 + rA;
  const int bidx = rc / Tc;
  const int tl   = rc - bidx * Tc;
  const int grow = bidx * Tn + t0 + tl;
  const float* Apt = X + (size_t)grow * Dn + kbase;

  // compute: wave w -> n-tiles {w*16, w*16+64}, m-subtiles {0,16}
  const int w    = tid >> 6;
  const int lane = tid & 63;
  const int mA   = lane & 15;         // A row / B col index supplied
  const int kq   = lane >> 4;         // k index supplied (0..3)
  const int n0   = w * 16;

  // --- D-layout probe: D[i][j] = 16*i + j ------------------------------
  int drow[4], dcol[4];
  {
    const double ap  = (kq == 0) ? (double)(16 * mA) : (kq == 1 ? 1.0 : 0.0);
    const double bpv = (kq == 0) ? 1.0 : (kq == 1 ? (double)mA : 0.0);
    double4_t pz = {0.0, 0.0, 0.0, 0.0};
    pz = __builtin_amdgcn_mfma_f64_16x16x4f64(ap, bpv, pz, 0, 0, 0);
    #pragma unroll
    for (int r = 0; r < 4; ++r) {
      const int p = (int)pz[r];
      drow[r] = p >> 4;
      dcol[r] = p & 15;
    }
  }

  double4_t acc00 = {0.0, 0.0, 0.0, 0.0};  // m-sub 0, n-tile 0
  double4_t acc01 = {0.0, 0.0, 0.0, 0.0};  // m-sub 0, n-tile 1
  double4_t acc10 = {0.0, 0.0, 0.0, 0.0};  // m-sub 1, n-tile 0
  double4_t acc11 = {0.0, 0.0, 0.0, 0.0};  // m-sub 1, n-tile 1

  // prefetch sub-chunk 0: 4 float4 per thread (32 m x 128 k / 256 thr)
  float4 pf[4];
  #pragma unroll
  for (int j = 0; j < 4; ++j)
    pf[j] = *(const float4*)(Apt + 4 * (c8 + j * 8));

  int buf = 0;
  for (int s = 0; s < NS; ++s) {
    // write staged registers into LDS buffer `buf` ([m][k] layout):
    // one ds_write_b128 per float4, conflict-free start-bank pattern
    #pragma unroll
    for (int j = 0; j < 4; ++j)
      *(float4*)&As[buf][rA][4 * (c8 + j * 8)] = pf[j];
    __syncthreads();

    // prefetch sub-chunk s+1 (overlaps compute below)
    if (s + 1 < NS) {
      #pragma unroll
      for (int j = 0; j < 4; ++j)
        pf[j] = *(const float4*)(Apt + (s + 1) * SC + 4 * (c8 + j * 8));
    }

    const double* bp = W1d + (size_t)(kbase + s * SC + kq) * Hn + n0 + mA;

    // ---- software-pipelined K loop: NK=32 steps of 4 k each -------------
    constexpr int NK = SC / 4;        // 32
    double a0r[2], a1r[2];            // LDS a, depth-2 rolling
    double b0r[4], b1r[4];            // L2  b, depth-4 rolling

    a0r[0] = (double)As[buf][mA][kq];
    a1r[0] = (double)As[buf][16 + mA][kq];
    #pragma unroll
    for (int i = 0; i < 3; ++i) {
      b0r[i] = bp[(size_t)(4 * i) * Hn];
      b1r[i] = bp[(size_t)(4 * i) * Hn + 64];
    }

    #pragma unroll
    for (int i = 0; i < NK; ++i) {
      if (i + 1 < NK) {               // a for iter i+1 (128cy lookahead)
        a0r[(i + 1) & 1] = (double)As[buf][mA][4 * (i + 1) + kq];
        a1r[(i + 1) & 1] = (double)As[buf][16 + mA][4 * (i + 1) + kq];
      }
      if (i + 3 < NK) {               // b for iter i+3 (256cy lookahead)
        b0r[(i + 3) & 3] = bp[(size_t)(4 * (i + 3)) * Hn];
        b1r[(i + 3) & 3] = bp[(size_t)(4 * (i + 3)) * Hn + 64];
      }
      const double a0 = a0r[i & 1];
      const double a1 = a1r[i & 1];
      const double b0 = b0r[i & 3];
      const double b1 = b1r[i & 3];
      acc00 = __builtin_amdgcn_mfma_f64_16x16x4f64(a0, b0, acc00, 0, 0, 0);
      acc01 = __builtin_amdgcn_mfma_f64_16x16x4f64(a0, b1, acc01, 0, 0, 0);
      acc10 = __builtin_amdgcn_mfma_f64_16x16x4f64(a1, b0, acc10, 0, 0, 0);
      acc11 = __builtin_amdgcn_mfma_f64_16x16x4f64(a1, b1, acc11, 0, 0, 0);
    }
    buf ^= 1;
  }

  // epilogue: atomic-add partial K-quarter into Hc (memset-zeroed base)
  #pragma unroll
  for (int r = 0; r < 4; ++r) {
    double* e00 = &Hc[(size_t)(m0 + drow[r]) * Hn + n0 + dcol[r]];
    double* e01 = &Hc[(size_t)(m0 + drow[r]) * Hn + n0 + 64 + dcol[r]];
    double* e10 = &Hc[(size_t)(m0 + 16 + drow[r]) * Hn + n0 + dcol[r]];
    double* e11 = &Hc[(size_t)(m0 + 16 + drow[r]) * Hn + n0 + 64 + dcol[r]];
    __hip_atomic_fetch_add(e00, acc00[r], __ATOMIC_RELAXED, __HIP_MEMORY_SCOPE_AGENT);
    __hip_atomic_fetch_add(e01, acc01[r], __ATOMIC_RELAXED, __HIP_MEMORY_SCOPE_AGENT);
    __hip_atomic_fetch_add(e10, acc10[r], __ATOMIC_RELAXED, __HIP_MEMORY_SCOPE_AGENT);
    __hip_atomic_fetch_add(e11, acc11[r], __ATOMIC_RELAXED, __HIP_MEMORY_SCOPE_AGENT);
  }
}

// ---------------------------------------------------------------------------
// Phase 2 scan, v2 — UNCHANGED from R12 (dropped out of top-5; was 137us).
// Ballot-based spike masks + parallel (t,c) dot-products + 5-thread v2 chain.
// ---------------------------------------------------------------------------
constexpr int TCMAX = 50;

__global__ __launch_bounds__(256) void snn_scan_v2(
    const double* __restrict__ Hc, const float* __restrict__ b1,
    const float* __restrict__ W2, const float* __restrict__ b2,
    double* __restrict__ v1s, double* __restrict__ v2s,
    double* __restrict__ accs, float* __restrict__ out, int t0, int Tc)
{
#pragma clang fp contract(off)
  __shared__ __align__(16) double HcL[TCMAX * Hn];        // 51200 B
  __shared__ double W2d[Hn * Cn];                          // 5120 B
  __shared__ double Pp[TCMAX * Cn];                        // 2000 B
  __shared__ unsigned long long Mk[TCMAX][2];              // 800 B

  const int b   = blockIdx.x;
  const int tid = threadIdx.x;

  // ---- P0: stage W2 (f32->f64) and the Hc row-slice into LDS -------------
  for (int i = tid; i < Hn * Cn; i += 256)
    W2d[i] = (double)W2[i];
  {
    const double* src = Hc + (size_t)b * Tc * Hn;
    const int nd2 = Tc * (Hn / 2);            // double2 elements
    int i = tid;
    for (; i + 3 * 256 < nd2; i += 4 * 256) { // 4-deep load pipeline
      double2 a0 = *(const double2*)(src + 2 * (i + 0 * 256));
      double2 a1 = *(const double2*)(src + 2 * (i + 1 * 256));
      double2 a2 = *(const double2*)(src + 2 * (i + 2 * 256));
      double2 a3 = *(const double2*)(src + 2 * (i + 3 * 256));
      *(double2*)&HcL[2 * (i + 0 * 256)] = a0;
      *(double2*)&HcL[2 * (i + 1 * 256)] = a1;
      *(double2*)&HcL[2 * (i + 2 * 256)] = a2;
      *(double2*)&HcL[2 * (i + 3 * 256)] = a3;
    }
    for (; i < nd2; i += 256)
      *(double2*)&HcL[2 * i] = *(const double2*)(src + 2 * i);
  }
  __syncthreads();

  // ---- P1: wave 0 runs the layer-1 LIF chain, emitting spike masks -------
  if (tid < 64) {
    const int lane = tid;
    const int j0   = lane * 2;
    const double b1a = (double)b1[j0];
    const double b1b = (double)b1[j0 + 1];

    double v1a, v1b;
    if (t0 == 0) { v1a = 0.0; v1b = 0.0; }
    else {
      v1a = v1s[(size_t)b * Hn + j0];
      v1b = v1s[(size_t)b * Hn + j0 + 1];
    }

    double2 hnext = *(const double2*)&HcL[j0];         // t = 0
    for (int t = 0; t < Tc; ++t) {
      const double2 hc = hnext;
      const int tn = (t + 1 < Tc) ? (t + 1) : t;
      hnext = *(const double2*)&HcL[tn * Hn + j0];     // 1-ahead prefetch

      // v1 = (v1*d1 + h) + b1  (left-assoc, separate roundings — unchanged)
      v1a = (v1a * D1 + hc.x) + b1a;
      v1b = (v1b * D1 + hc.y) + b1b;
      const bool ca = (v1a >= 1.0);
      const bool cb = (v1b >= 1.0);
      const unsigned long long mA = __ballot(ca);      // neuron 2L  <- bit L
      const unsigned long long mB = __ballot(cb);      // neuron 2L+1<- bit L
      if (ca) v1a = 0.0;
      if (cb) v1b = 0.0;
      if (lane == 0) { Mk[t][0] = mA; Mk[t][1] = mB; }
    }
    v1s[(size_t)b * Hn + j0]     = v1a;
    v1s[(size_t)b * Hn + j0 + 1] = v1b;
  }
  __syncthreads();

  // ---- P2: all (t,c) classifier dot-products in parallel ------------------
  // p[t][c] = sum_j spike[j,t] * W2[j,c]; spike bits from masks; summation
  // order j-ascending (exactness: integer-count output, huge spike margins).
  for (int pi = tid; pi < Tc * Cn; pi += 256) {
    const int tt = pi / Cn;
    const int cc = pi - tt * Cn;
    const unsigned long long mA = Mk[tt][0];
    const unsigned long long mB = Mk[tt][1];
    double sA = 0.0, sB = 0.0;
    #pragma unroll
    for (int L = 0; L < 64; ++L) {
      sA += ((mA >> L) & 1ull) ? W2d[(2 * L) * Cn + cc]     : 0.0;
      sB += ((mB >> L) & 1ull) ? W2d[(2 * L + 1) * Cn + cc] : 0.0;
    }
    Pp[pi] = sA + sB;
  }
  __syncthreads();

  // ---- P3: per-class v2/acc chains (5 independent threads) ----------------
  if (tid < Cn) {
    const int c = tid;
    const double bb2 = (double)b2[c];
    double v2, acc;
    if (t0 == 0) { v2 = 0.0; acc = 0.0; }
    else {
      v2  = v2s[(size_t)b * Cn + c];
      acc = accs[(size_t)b * Cn + c];
    }
    double pn = Pp[c];                                  // t = 0
    for (int t = 0; t < Tc; ++t) {
      const double p = pn;
      const int tn = (t + 1 < Tc) ? (t + 1) : t;
      pn = Pp[tn * Cn + c];                             // 1-ahead prefetch
      const double v = ((v2 * D2) + p) + bb2;           // unchanged order
      const bool s2 = (v >= 1.0);
      v2 = s2 ? 0.0 : v;
      acc += s2 ? 1.0 : 0.0;
    }
    v2s[(size_t)b * Cn + c]  = v2;
    accs[(size_t)b * Cn + c] = acc;
    if (t0 + Tc == Tn)
      out[(size_t)b * Cn + c] = (float)(acc / 100.0);
  }
}

// ---------------------------------------------------------------------------
extern "C" void kernel_launch(void* const* d_in, const int* in_sizes, int n_in,
                              void* d_out, int out_size, void* d_ws, size_t ws_size,
                              hipStream_t stream) {
  const float* X  = (const float*)d_in[0];   // [B,T,D]
  const float* W1 = (const float*)d_in[1];   // [D,H]
  const float* b1 = (const float*)d_in[2];   // [H]
  const float* W2 = (const float*)d_in[3];   // [H,C]
  const float* b2 = (const float*)d_in[4];   // [C]
  float* out = (float*)d_out;                // [B,C]

  // ws layout: W1d (1 MB) | Hc [B*Tc,H] | v1s | v2s | accs   (all f64)
  // Tc capped at TCMAX=50 so the scan's LDS staging fits 64KB static.
  const size_t w1Doubles    = (size_t)Dn * Hn;                    // 131072
  const size_t stateDoubles = (size_t)Bsz * Hn + 2 * (size_t)Bsz * Cn;
  static const int cands[] = {50, 25, 20, 10, 5, 4, 2, 1};
  int Tc = 1;
  for (int i = 0; i < 8; ++i) {
    const size_t need =
        (w1Doubles + (size_t)Bsz * cands[i] * Hn + stateDoubles) * sizeof(double);
    if (need <= ws_size) { Tc = cands[i]; break; }
  }

  double* W1d  = (double*)d_ws;
  double* Hc   = W1d + w1Doubles;                    // [B*Tc, H]
  double* v1s  = Hc  + (size_t)Bsz * Tc * Hn;        // [B, H]
  double* v2s  = v1s + (size_t)Bsz * Hn;             // [B, C]
  double* accs = v2s + (size_t)Bsz * Cn;             // [B, C]
  const size_t hcBytes = (size_t)Bsz * Tc * Hn * sizeof(double);

  cvt_w1<<<dim3((Dn * Hn) / (256 * 4)), dim3(256), 0, stream>>>(W1, W1d);

  for (int t0 = 0; t0 < Tn; t0 += Tc) {
    const int rows = Bsz * Tc;
    hipMemsetAsync(Hc, 0, hcBytes, stream);          // atomic accumulation base
    gemm_mfma_f64<<<dim3((rows / TILE_M) * KSPL), dim3(256), 0, stream>>>(
        X, W1d, Hc, t0, Tc);
    snn_scan_v2<<<dim3(Bsz), dim3(256), 0, stream>>>(Hc, b1, W2, b2,
                                                     v1s, v2s, accs, out, t0, Tc);
  }
}

// Round 6
// 272.118 us; speedup vs baseline: 1.1518x; 1.1518x over previous
//
#include <hip/hip_runtime.h>

// Problem dims (fixed by the reference): B=256, T=100, D=1024, H=128, C=5
constexpr int Bsz = 256;
constexpr int Tn  = 100;
constexpr int Dn  = 1024;
constexpr int Hn  = 128;
constexpr int Cn  = 5;

// float64 values of np.exp(-1/10), np.exp(-1/20)
#define D1 0.9048374180359595731642491
#define D2 0.9512294245007140090914253

typedef double double4_t __attribute__((ext_vector_type(4)));

// ---------------------------------------------------------------------------
// R14: dispatch-count attack. Ledger across R11-R13 shows ~15-20us overhead
// PER DISPATCH (gap between summed kernel time and bench total grows 43us
// when going 4->7 dispatches/iter), and gemm split as 2x1600 blocks (161us)
// is slower than one 3200-block dispatch (<137us, R11) from per-dispatch
// ramp/tail. Changes (gemm inner loop untouched — R13 proved source-ILP
// is exhausted):
//  * Tc=100 single chunk: 1 gemm + 1 scan + 1 memset = 3 dispatches (was 7).
//  * cvt_w1 folded into gemm: B loaded f32 + v_cvt_f64_f32 in-loop (exact,
//    +2 VALU per 256cy-MFMA iter; halves B L2 traffic; drops W1d ws).
//  * scan v3: Tc=100 in one kernel, Hc staged in two 50-step halves
//    (LDS 60.5KB), no inter-chunk state, writes out directly.
// ws = Hc only: 256*100*128*8 = 26.2MB (baseline proved ws>=27.4MB).
// ---------------------------------------------------------------------------
constexpr int TILE_M = 32;
constexpr int KSPL   = 4;
constexpr int KH     = Dn / KSPL;     // 256 k per block
constexpr int SC     = 128;           // staging sub-chunk (k)
constexpr int NS     = KH / SC;       // 2
constexpr int KPAD   = 132;           // 128 k + 4 pad (f32)

__global__ __launch_bounds__(256) void gemm_mfma_f64(
    const float* __restrict__ X, const float* __restrict__ W1,
    double* __restrict__ Hc, int t0, int Tc)
{
  // As[buf][m][k] : 2 * 32 * 132 * 4 = 33792 B
  __shared__ __align__(16) float As[2][TILE_M][KPAD];

  const int tid   = threadIdx.x;
  const int mt    = blockIdx.x >> 2;
  const int kspl  = blockIdx.x & 3;
  const int m0    = mt * TILE_M;
  const int kbase = kspl * KH;

  // staging: thread t -> A row rA=t>>3 (0..31), float4 k-group c8=t&7 (+ j*8)
  const int rA = tid >> 3;
  const int c8 = tid & 7;
  const int rc   = m0 + rA;
  const int bidx = rc / Tc;
  const int tl   = rc - bidx * Tc;
  const int grow = bidx * Tn + t0 + tl;
  const float* Apt = X + (size_t)grow * Dn + kbase;

  // compute: wave w -> n-tiles {w*16, w*16+64}, m-subtiles {0,16}
  const int w    = tid >> 6;
  const int lane = tid & 63;
  const int mA   = lane & 15;         // A row / B col index supplied
  const int kq   = lane >> 4;         // k index supplied (0..3)
  const int n0   = w * 16;

  // --- D-layout probe: D[i][j] = 16*i + j ------------------------------
  int drow[4], dcol[4];
  {
    const double ap  = (kq == 0) ? (double)(16 * mA) : (kq == 1 ? 1.0 : 0.0);
    const double bpv = (kq == 0) ? 1.0 : (kq == 1 ? (double)mA : 0.0);
    double4_t pz = {0.0, 0.0, 0.0, 0.0};
    pz = __builtin_amdgcn_mfma_f64_16x16x4f64(ap, bpv, pz, 0, 0, 0);
    #pragma unroll
    for (int r = 0; r < 4; ++r) {
      const int p = (int)pz[r];
      drow[r] = p >> 4;
      dcol[r] = p & 15;
    }
  }

  double4_t acc00 = {0.0, 0.0, 0.0, 0.0};  // m-sub 0, n-tile 0
  double4_t acc01 = {0.0, 0.0, 0.0, 0.0};  // m-sub 0, n-tile 1
  double4_t acc10 = {0.0, 0.0, 0.0, 0.0};  // m-sub 1, n-tile 0
  double4_t acc11 = {0.0, 0.0, 0.0, 0.0};  // m-sub 1, n-tile 1

  // prefetch sub-chunk 0: 4 float4 per thread (32 m x 128 k / 256 thr)
  float4 pf[4];
  #pragma unroll
  for (int j = 0; j < 4; ++j)
    pf[j] = *(const float4*)(Apt + 4 * (c8 + j * 8));

  int buf = 0;
  for (int s = 0; s < NS; ++s) {
    // write staged registers into LDS buffer `buf` ([m][k] layout):
    // one ds_write_b128 per float4, conflict-free start-bank pattern
    #pragma unroll
    for (int j = 0; j < 4; ++j)
      *(float4*)&As[buf][rA][4 * (c8 + j * 8)] = pf[j];
    __syncthreads();

    // prefetch sub-chunk s+1 (overlaps compute below)
    if (s + 1 < NS) {
      #pragma unroll
      for (int j = 0; j < 4; ++j)
        pf[j] = *(const float4*)(Apt + (s + 1) * SC + 4 * (c8 + j * 8));
    }

    // B now read as f32 directly from W1, converted in-loop (exact)
    const float* bp = W1 + (size_t)(kbase + s * SC + kq) * Hn + n0 + mA;

    // ---- software-pipelined K loop: NK=32 steps of 4 k each -------------
    constexpr int NK = SC / 4;        // 32
    double a0r[2], a1r[2];            // LDS a, depth-2 rolling
    double b0r[4], b1r[4];            // L2  b, depth-4 rolling

    a0r[0] = (double)As[buf][mA][kq];
    a1r[0] = (double)As[buf][16 + mA][kq];
    #pragma unroll
    for (int i = 0; i < 3; ++i) {
      b0r[i] = (double)bp[(size_t)(4 * i) * Hn];
      b1r[i] = (double)bp[(size_t)(4 * i) * Hn + 64];
    }

    #pragma unroll
    for (int i = 0; i < NK; ++i) {
      if (i + 1 < NK) {               // a for iter i+1
        a0r[(i + 1) & 1] = (double)As[buf][mA][4 * (i + 1) + kq];
        a1r[(i + 1) & 1] = (double)As[buf][16 + mA][4 * (i + 1) + kq];
      }
      if (i + 3 < NK) {               // b for iter i+3
        b0r[(i + 3) & 3] = (double)bp[(size_t)(4 * (i + 3)) * Hn];
        b1r[(i + 3) & 3] = (double)bp[(size_t)(4 * (i + 3)) * Hn + 64];
      }
      const double a0 = a0r[i & 1];
      const double a1 = a1r[i & 1];
      const double b0 = b0r[i & 3];
      const double b1 = b1r[i & 3];
      acc00 = __builtin_amdgcn_mfma_f64_16x16x4f64(a0, b0, acc00, 0, 0, 0);
      acc01 = __builtin_amdgcn_mfma_f64_16x16x4f64(a0, b1, acc01, 0, 0, 0);
      acc10 = __builtin_amdgcn_mfma_f64_16x16x4f64(a1, b0, acc10, 0, 0, 0);
      acc11 = __builtin_amdgcn_mfma_f64_16x16x4f64(a1, b1, acc11, 0, 0, 0);
    }
    buf ^= 1;
  }

  // epilogue: atomic-add partial K-quarter into Hc (memset-zeroed base)
  #pragma unroll
  for (int r = 0; r < 4; ++r) {
    double* e00 = &Hc[(size_t)(m0 + drow[r]) * Hn + n0 + dcol[r]];
    double* e01 = &Hc[(size_t)(m0 + drow[r]) * Hn + n0 + 64 + dcol[r]];
    double* e10 = &Hc[(size_t)(m0 + 16 + drow[r]) * Hn + n0 + dcol[r]];
    double* e11 = &Hc[(size_t)(m0 + 16 + drow[r]) * Hn + n0 + 64 + dcol[r]];
    __hip_atomic_fetch_add(e00, acc00[r], __ATOMIC_RELAXED, __HIP_MEMORY_SCOPE_AGENT);
    __hip_atomic_fetch_add(e01, acc01[r], __ATOMIC_RELAXED, __HIP_MEMORY_SCOPE_AGENT);
    __hip_atomic_fetch_add(e10, acc10[r], __ATOMIC_RELAXED, __HIP_MEMORY_SCOPE_AGENT);
    __hip_atomic_fetch_add(e11, acc11[r], __ATOMIC_RELAXED, __HIP_MEMORY_SCOPE_AGENT);
  }
}

// ---------------------------------------------------------------------------
// Phase 2 scan v3: full T=100 in ONE dispatch, Hc staged in two 50-step
// halves (LDS cap). Same proven v2 algorithm: ballot spike masks, parallel
// (t,c) dot products, 5-thread v2 chains. No inter-chunk state, writes out.
// LDS: 51200 + 5120 + 4000 + 1600 = 61920 B < 64KB.
// ---------------------------------------------------------------------------
constexpr int THALF = 50;

__global__ __launch_bounds__(256) void snn_scan_v3(
    const double* __restrict__ Hc, const float* __restrict__ b1,
    const float* __restrict__ W2, const float* __restrict__ b2,
    float* __restrict__ out)
{
#pragma clang fp contract(off)
  __shared__ __align__(16) double HcL[THALF * Hn];        // 51200 B
  __shared__ double W2d[Hn * Cn];                          // 5120 B
  __shared__ double Pp[Tn * Cn];                           // 4000 B
  __shared__ unsigned long long Mk[Tn][2];                 // 1600 B

  const int b   = blockIdx.x;
  const int tid = threadIdx.x;

  // W2 (f32->f64) into LDS once
  for (int i = tid; i < Hn * Cn; i += 256)
    W2d[i] = (double)W2[i];

  // layer-1 per-lane constants (j0 safe for all threads; only wave0 uses)
  const int j0 = (tid & 63) * 2;
  const double b1a = (double)b1[j0];
  const double b1b = (double)b1[j0 + 1];
  double v1a = 0.0, v1b = 0.0;                  // t0 == 0 always (Tc = Tn)

  const double* hsrc = Hc + (size_t)b * Tn * Hn;

  for (int h = 0; h < 2; ++h) {
    if (h) __syncthreads();                     // P1(h-1) done before restage

    // ---- stage half h of Hc into LDS (all 256 threads) -------------------
    {
      const double* src = hsrc + (size_t)h * THALF * Hn;
      const int nd2 = THALF * (Hn / 2);         // 3200 double2
      int i = tid;
      for (; i + 3 * 256 < nd2; i += 4 * 256) { // 4-deep load pipeline
        double2 a0 = *(const double2*)(src + 2 * (i + 0 * 256));
        double2 a1 = *(const double2*)(src + 2 * (i + 1 * 256));
        double2 a2 = *(const double2*)(src + 2 * (i + 2 * 256));
        double2 a3 = *(const double2*)(src + 2 * (i + 3 * 256));
        *(double2*)&HcL[2 * (i + 0 * 256)] = a0;
        *(double2*)&HcL[2 * (i + 1 * 256)] = a1;
        *(double2*)&HcL[2 * (i + 2 * 256)] = a2;
        *(double2*)&HcL[2 * (i + 3 * 256)] = a3;
      }
      for (; i < nd2; i += 256)
        *(double2*)&HcL[2 * i] = *(const double2*)(src + 2 * i);
    }
    __syncthreads();

    // ---- P1: wave 0 runs the layer-1 LIF chain for this half --------------
    if (tid < 64) {
      const int lane = tid;
      double2 hnext = *(const double2*)&HcL[j0];
      for (int t = 0; t < THALF; ++t) {
        const double2 hc = hnext;
        const int tn = (t + 1 < THALF) ? (t + 1) : t;
        hnext = *(const double2*)&HcL[tn * Hn + j0];   // 1-ahead prefetch

        // v1 = (v1*d1 + h) + b1  (left-assoc, separate roundings)
        v1a = (v1a * D1 + hc.x) + b1a;
        v1b = (v1b * D1 + hc.y) + b1b;
        const bool ca = (v1a >= 1.0);
        const bool cb = (v1b >= 1.0);
        const unsigned long long mA = __ballot(ca);    // neuron 2L   <- bit L
        const unsigned long long mB = __ballot(cb);    // neuron 2L+1 <- bit L
        if (ca) v1a = 0.0;
        if (cb) v1b = 0.0;
        if (lane == 0) { Mk[h * THALF + t][0] = mA; Mk[h * THALF + t][1] = mB; }
      }
    }
  }
  __syncthreads();

  // ---- P2: all (t,c) classifier dot-products in parallel -------------------
  for (int pi = tid; pi < Tn * Cn; pi += 256) {
    const int tt = pi / Cn;
    const int cc = pi - tt * Cn;
    const unsigned long long mA = Mk[tt][0];
    const unsigned long long mB = Mk[tt][1];
    double sA = 0.0, sB = 0.0;
    #pragma unroll
    for (int L = 0; L < 64; ++L) {
      sA += ((mA >> L) & 1ull) ? W2d[(2 * L) * Cn + cc]     : 0.0;
      sB += ((mB >> L) & 1ull) ? W2d[(2 * L + 1) * Cn + cc] : 0.0;
    }
    Pp[pi] = sA + sB;
  }
  __syncthreads();

  // ---- P3: per-class v2/acc chains (5 independent threads) -----------------
  if (tid < Cn) {
    const int c = tid;
    const double bb2 = (double)b2[c];
    double v2 = 0.0, acc = 0.0;
    double pn = Pp[c];                                  // t = 0
    for (int t = 0; t < Tn; ++t) {
      const double p = pn;
      const int tn = (t + 1 < Tn) ? (t + 1) : t;
      pn = Pp[tn * Cn + c];                             // 1-ahead prefetch
      const double v = ((v2 * D2) + p) + bb2;           // unchanged order
      const bool s2 = (v >= 1.0);
      v2 = s2 ? 0.0 : v;
      acc += s2 ? 1.0 : 0.0;
    }
    out[(size_t)b * Cn + c] = (float)(acc / 100.0);
  }
}

// ---------------------------------------------------------------------------
extern "C" void kernel_launch(void* const* d_in, const int* in_sizes, int n_in,
                              void* d_out, int out_size, void* d_ws, size_t ws_size,
                              hipStream_t stream) {
  const float* X  = (const float*)d_in[0];   // [B,T,D]
  const float* W1 = (const float*)d_in[1];   // [D,H]
  const float* b1 = (const float*)d_in[2];   // [H]
  const float* W2 = (const float*)d_in[3];   // [H,C]
  const float* b2 = (const float*)d_in[4];   // [C]
  float* out = (float*)d_out;                // [B,C]

  // ws = Hc [B*Tn, H] f64 = 26.2MB (baseline proved ws >= 27.4MB)
  double* Hc = (double*)d_ws;
  const size_t hcBytes = (size_t)Bsz * Tn * Hn * sizeof(double);

  hipMemsetAsync(Hc, 0, hcBytes, stream);            // atomic accumulation base
  gemm_mfma_f64<<<dim3((Bsz * Tn / TILE_M) * KSPL), dim3(256), 0, stream>>>(
      X, W1, Hc, 0, Tn);
  snn_scan_v3<<<dim3(Bsz), dim3(256), 0, stream>>>(Hc, b1, W2, b2, out);
}